// Round 1
// baseline (3581.145 us; speedup 1.0000x reference)
//
#include <hip/hip_runtime.h>
#include <math.h>

#define NPOOL 4096
#define NSEQ  512
#define NF    20
#define EDIM  64
#define GDIM  128
#define SDIM  16
#define ALPH  20

__device__ __forceinline__ double relu_d(double x){ return x > 0.0 ? x : 0.0; }
__device__ __forceinline__ double sigm_d(double x){ return 1.0 / (1.0 + exp(-x)); }

// Fin[i][e] = f @ w_feat + b_feat (f64); R = relu(Fin)
__global__ __launch_bounds__(256) void k_prep(const float* __restrict__ f, const float* __restrict__ wf,
                       const float* __restrict__ bf, double* __restrict__ Fin, double* __restrict__ R) {
    int t = blockIdx.x * 256 + threadIdx.x;   // NPOOL*EDIM
    int i = t >> 6, e = t & 63;
    double acc = (double)bf[e];
#pragma unroll
    for (int j = 0; j < NF; ++j)
        acc += (double)f[i * NF + j] * (double)wf[j * EDIM + e];
    Fin[t] = acc;
    R[t] = acc > 0.0 ? acc : 0.0;
}

// seq_embed = x @ w_seq + b_seq (f64)
__global__ __launch_bounds__(256) void k_seqe(const float* __restrict__ x, const float* __restrict__ wsq,
                       const float* __restrict__ bsq, double* __restrict__ seqe) {
    int t = blockIdx.x * 256 + threadIdx.x;   // NSEQ*SDIM = 8192
    int k = t >> 4, s = t & 15;
    double acc = (double)bsq[s];
#pragma unroll
    for (int q = 0; q < ALPH; ++q)
        acc += (double)x[k * ALPH + q] * (double)wsq[q * SDIM + s];
    seqe[t] = acc;
}

// C(4096x64 f64) = A(4096x4096 f32) @ B(4096x64 f64).  BM=8, BK=64.
__global__ __launch_bounds__(256) void gemm_f64(const float* __restrict__ A, const double* __restrict__ B,
                                                double* __restrict__ C) {
    const int N = NPOOL;
    __shared__ double Bs[64 * 64];   // 32 KB
    __shared__ double As[8 * 64];    // 4 KB
    int tid = threadIdx.x;
    int c = tid & 63;
    int rg = tid >> 6;               // 0..3
    int row0 = blockIdx.x * 8;
    double acc0 = 0.0, acc1 = 0.0;
    for (int kt = 0; kt < N; kt += 64) {
        const double* Bt = B + (size_t)kt * 64;
#pragma unroll
        for (int i = 0; i < 16; ++i) {
            int idx = i * 256 + tid;
            Bs[idx] = Bt[idx];
        }
#pragma unroll
        for (int i = 0; i < 2; ++i) {
            int idx = i * 256 + tid;
            int r = idx >> 6, kk = idx & 63;
            As[idx] = (double)A[(size_t)(row0 + r) * N + kt + kk];
        }
        __syncthreads();
        const double* As0 = As + rg * 64;
        const double* As1 = As + (rg + 4) * 64;
#pragma unroll
        for (int kk = 0; kk < 64; ++kk) {
            double b = Bs[kk * 64 + c];
            acc0 = fma(As0[kk], b, acc0);
            acc1 = fma(As1[kk], b, acc1);
        }
        __syncthreads();
    }
    C[(size_t)(row0 + rg) * 64 + c] = acc0;
    C[(size_t)(row0 + rg + 4) * 64 + c] = acc1;
}

// s[i] = relu(T3[i,:] @ w_gcn1) . w_edge[0:64]   (one wave per row)
__global__ __launch_bounds__(256) void k_head(const double* __restrict__ T3, const float* __restrict__ w1,
                       const float* __restrict__ we, double* __restrict__ s) {
    int row = (blockIdx.x * 256 + threadIdx.x) >> 6;
    int e = threadIdx.x & 63;
    const double* r = T3 + (size_t)row * 64;
    double h = 0.0;
#pragma unroll
    for (int c = 0; c < 64; ++c)
        h += r[c] * (double)w1[c * 64 + e];
    double p = (h > 0.0 ? h : 0.0) * (double)we[e];
    for (int off = 32; off; off >>= 1) p += __shfl_down(p, off, 64);
    if (e == 0) s[row] = p;
}

// full bitonic sort of 4096 (desc by key, asc by index on ties)
__global__ __launch_bounds__(1024) void k_sort(const double* __restrict__ s, int* __restrict__ order,
                        double* __restrict__ skey, int* __restrict__ idxs_sel) {
    __shared__ double key[NPOOL];
    __shared__ int    idx[NPOOL];
    for (int t = threadIdx.x; t < NPOOL; t += 1024) { key[t] = s[t]; idx[t] = t; }
    __syncthreads();
    for (int k = 2; k <= NPOOL; k <<= 1) {
        for (int j = k >> 1; j > 0; j >>= 1) {
            for (int t = threadIdx.x; t < NPOOL; t += 1024) {
                int l = t ^ j;
                if (l > t) {
                    double ka = key[t], kb = key[l];
                    int ia = idx[t], ib = idx[l];
                    bool aLess = (ka > kb) || (ka == kb && ia < ib);  // "earlier in final order"
                    bool asc = ((t & k) == 0);
                    bool doSwap = asc ? !aLess : aLess;
                    if (doSwap) { key[t] = kb; key[l] = ka; idx[t] = ib; idx[l] = ia; }
                }
            }
            __syncthreads();
        }
    }
    for (int t = threadIdx.x; t < NSEQ; t += 1024) {
        order[t] = idx[t]; skey[t] = key[t]; idxs_sel[t] = idx[t];
    }
}

// per-k parallel recurrence pieces (assuming selection == sorted prefix)
__global__ __launch_bounds__(256) void k_perk(const double* __restrict__ Fin, const int* __restrict__ order,
                       const float* __restrict__ w2, const float* __restrict__ wgr, const float* __restrict__ bgr,
                       const float* __restrict__ wga, const float* __restrict__ bga,
                       double* __restrict__ phi_inf, double* __restrict__ phi_pair, double* __restrict__ hlast) {
    const double r2 = 0.70710678118654752440;
    const double r3 = 0.57735026918962576451;
    __shared__ double u[4][64];
    __shared__ double comb[3][64];
    __shared__ double v[3][64];
    __shared__ double hgg[3][2][GDIM];
    int k = blockIdx.x;
    int t = threadIdx.x;
    {
        int w = t >> 6, e = t & 63;
        int j = k - 3 + w;
        u[w][e] = (j >= 0) ? Fin[(size_t)order[j] * 64 + e] : 0.0;
    }
    __syncthreads();
    if (t < 192) {
        int w = t >> 6, e = t & 63;
        double dh_km3 = (k - 3 == 0) ? r2 : r3;
        double dh_km2 = (k - 2 == 0) ? r2 : r3;
        double dh_km1 = (k - 1 == 0) ? r2 : r3;
        double outer, c0, c1, c2, c3;
        if (w == 0) {        // v_{k-2} (final form)
            outer = dh_km2; c0 = dh_km3; c1 = dh_km2; c2 = dh_km1; c3 = 0.0;
        } else if (w == 1) { // v_{k-1}^{(k)}
            outer = dh_km1; c0 = 0.0; c1 = dh_km2; c2 = dh_km1; c3 = r2;
        } else {             // v_k^{(k)}
            if (k == 0) { outer = 1.0; c0 = c1 = c2 = 0.0; c3 = 1.0; }
            else        { outer = r2;  c0 = c1 = 0.0; c2 = dh_km1; c3 = r2; }
        }
        comb[w][e] = outer * (c0 * u[0][e] + c1 * u[1][e] + c2 * u[2][e] + c3 * u[3][e]);
    }
    __syncthreads();
    if (t < 192) {
        int w = t >> 6, e = t & 63;
        double acc = 0.0;
#pragma unroll
        for (int j = 0; j < 64; ++j)
            acc += comb[w][j] * (double)w2[j * 64 + e];
        v[w][e] = acc;
    }
    __syncthreads();
    for (int rep = 0; rep < 3; ++rep) {
        int d = t & 127, g = t >> 7;
        const float* W = g ? wga : wgr;
        const float* B = g ? bga : bgr;
        double acc = (double)B[d];
#pragma unroll
        for (int j = 0; j < 64; ++j)
            acc += v[rep][j] * (double)W[j * GDIM + d];
        hgg[rep][g][d] = acc;
    }
    __syncthreads();
    if (t < 128) {
        if (k >= 2) phi_inf[(size_t)(k - 2) * GDIM + t] = hgg[0][0][t] * sigm_d(hgg[0][1][t]);
        double pp = hgg[2][0][t] * sigm_d(hgg[2][1][t]);
        if (k >= 1) pp += hgg[1][0][t] * sigm_d(hgg[1][1][t]);
        phi_pair[(size_t)k * GDIM + t] = pp;
    } else if (t < 192) {
        hlast[(size_t)k * 64 + (t - 128)] = v[2][t - 128];
    }
}

// per-dim prefix scan: hgr[k] = sum_{j<=k-2} phi_inf[j] + phi_pair[k]
__global__ __launch_bounds__(512) void k_scan(const double* __restrict__ phi_inf, const double* __restrict__ phi_pair,
                       double* __restrict__ hgr) {
    __shared__ double sb[NSEQ];
    int d = blockIdx.x, t = threadIdx.x;
    sb[t] = (t >= 2) ? phi_inf[(size_t)(t - 2) * GDIM + d] : 0.0;
    for (int off = 1; off < NSEQ; off <<= 1) {
        __syncthreads();
        double add = (t >= off) ? sb[t - off] : 0.0;
        __syncthreads();
        sb[t] += add;
    }
    __syncthreads();
    hgr[(size_t)t * GDIM + d] = sb[t] + phi_pair[(size_t)t * GDIM + d];
}

// c_k from carried (k-1) state; one wave per k
__global__ __launch_bounds__(64) void k_c(const double* __restrict__ hlast, const double* __restrict__ hgr,
                   const double* __restrict__ seqe, const float* __restrict__ we, double* __restrict__ c) {
    int k = blockIdx.x, j = threadIdx.x;
    double ts = 0.0;
    if (k > 0) {
        ts += relu_d(hlast[(size_t)(k - 1) * 64 + j]) * (double)we[64 + j];
        ts += relu_d(hgr[(size_t)(k - 1) * GDIM + j]) * (double)we[144 + j];
        ts += relu_d(hgr[(size_t)(k - 1) * GDIM + 64 + j]) * (double)we[208 + j];
    }
    if (j < 16) ts += relu_d(seqe[(size_t)k * SDIM + j]) * (double)we[128 + j];
    for (int off = 32; off; off >>= 1) ts += __shfl_down(ts, off, 64);
    if (j == 0) c[k] = ts;
}

__global__ __launch_bounds__(512) void k_verify(const double* __restrict__ skey, const double* __restrict__ c,
                         int* __restrict__ flag) {
    __shared__ int bad;
    int t = threadIdx.x;
    if (t == 0) bad = 0;
    __syncthreads();
    if (t >= 1 && !(skey[t] + c[t] > 0.0)) atomicOr(&bad, 1);
    __syncthreads();
    if (t == 0) flag[0] = bad;
}

// exact sequential fallback (runs only when fast path invalid)
__global__ __launch_bounds__(256) void k_fallback(const int* __restrict__ flag,
        const double* __restrict__ Fin, const int* __restrict__ order, const double* __restrict__ skey,
        const double* __restrict__ seqe,
        const float* __restrict__ w2, const float* __restrict__ wgr, const float* __restrict__ bgr,
        const float* __restrict__ wga, const float* __restrict__ bga, const float* __restrict__ we,
        int* __restrict__ idxs_sel, double* __restrict__ c) {
    if (flag[0] == 0) return;
    const double r2 = 0.70710678118654752440;
    const double r3 = 0.57735026918962576451;
    __shared__ double u[4][64];
    __shared__ double comb[3][64];
    __shared__ double v[3][64];
    __shared__ double hgg[3][2][GDIM];
    __shared__ double Phi[GDIM], hgraph[GDIM], hlastS[64];
    __shared__ int selS, ptrS, minS_;
    int t = threadIdx.x;
    // init state
    if (t < 64) { u[0][t] = u[1][t] = u[2][t] = u[3][t] = 0.0; hlastS[t] = 0.0; }
    if (t < 128) { Phi[t] = 0.0; hgraph[t] = 0.0; }
    if (t == 0) { ptrS = 0; minS_ = 0x7fffffff; }
    __syncthreads();
    for (int k = 0; k < NSEQ; ++k) {
        if (t < 64) {
            int j = t;
            double ts = relu_d(hlastS[j]) * (double)we[64 + j]
                      + relu_d(hgraph[j]) * (double)we[144 + j]
                      + relu_d(hgraph[64 + j]) * (double)we[208 + j];
            if (j < 16) ts += relu_d(seqe[(size_t)k * SDIM + j]) * (double)we[128 + j];
            for (int off = 32; off; off >>= 1) ts += __shfl_down(ts, off, 64);
            if (j == 0) {
                c[k] = ts;
                int ptr = ptrS, idx;
                if (ptr == 0) { idx = order[0]; minS_ = idx; ptrS = 1; }
                else if (skey[ptr] + ts > 0.0) {
                    idx = order[ptr];
                    if (idx < minS_) minS_ = idx;
                    ptrS = ptr + 1;
                } else idx = minS_;
                selS = idx;
                idxs_sel[k] = idx;
            }
        }
        __syncthreads();
        int idx = selS;
        if (t < 64) u[k & 3][t] = Fin[(size_t)idx * 64 + t];
        __syncthreads();
        if (t < 192) {
            int w = t >> 6, e = t & 63;
            double dh_km3 = (k - 3 == 0) ? r2 : r3;
            double dh_km2 = (k - 2 == 0) ? r2 : r3;
            double dh_km1 = (k - 1 == 0) ? r2 : r3;
            double outer, c0, c1, c2, c3;
            if (w == 0) {
                outer = dh_km2; c0 = dh_km3; c1 = dh_km2; c2 = dh_km1; c3 = 0.0;
            } else if (w == 1) {
                outer = dh_km1; c0 = 0.0; c1 = dh_km2; c2 = dh_km1; c3 = r2;
            } else {
                if (k == 0) { outer = 1.0; c0 = c1 = c2 = 0.0; c3 = 1.0; }
                else        { outer = r2;  c0 = c1 = 0.0; c2 = dh_km1; c3 = r2; }
            }
            // circular slots: u_{k-3+w} lives in slot (k-3+w)&3; unwritten slots are zero
            double uu0 = u[(k - 3) & 3][e], uu1 = u[(k - 2) & 3][e], uu2 = u[(k - 1) & 3][e], uu3 = u[k & 3][e];
            comb[w][e] = outer * (c0 * uu0 + c1 * uu1 + c2 * uu2 + c3 * uu3);
        }
        __syncthreads();
        if (t < 192) {
            int w = t >> 6, e = t & 63;
            double acc = 0.0;
#pragma unroll
            for (int j = 0; j < 64; ++j)
                acc += comb[w][j] * (double)w2[j * 64 + e];
            v[w][e] = acc;
        }
        __syncthreads();
        for (int rep = 0; rep < 3; ++rep) {
            int d = t & 127, g = t >> 7;
            const float* W = g ? wga : wgr;
            const float* B = g ? bga : bgr;
            double acc = (double)B[d];
#pragma unroll
            for (int j = 0; j < 64; ++j)
                acc += v[rep][j] * (double)W[j * GDIM + d];
            hgg[rep][g][d] = acc;
        }
        __syncthreads();
        if (t < 128) {
            if (k >= 2) Phi[t] += hgg[0][0][t] * sigm_d(hgg[0][1][t]);
            double hg = Phi[t] + hgg[2][0][t] * sigm_d(hgg[2][1][t]);
            if (k >= 1) hg += hgg[1][0][t] * sigm_d(hgg[1][1][t]);
            hgraph[t] = hg;
        } else if (t < 192) {
            hlastS[t - 128] = v[2][t - 128];
        }
        __syncthreads();
    }
}

__global__ __launch_bounds__(256) void k_rank_init(int* __restrict__ rank) {
    rank[blockIdx.x * 256 + threadIdx.x] = 1 << 30;
}

__global__ __launch_bounds__(256) void k_rank_set(const int* __restrict__ idxs_sel, int* __restrict__ rank,
                           float* __restrict__ out) {
    int t = blockIdx.x * 256 + threadIdx.x;
    if (t < NSEQ) {
        atomicMin(&rank[idxs_sel[t]], t);
        out[(size_t)NSEQ * NPOOL + t] = (float)idxs_sel[t];
    }
}

__global__ __launch_bounds__(256) void k_fill(const double* __restrict__ s, const double* __restrict__ c,
                       const int* __restrict__ rank, const float* __restrict__ be, float* __restrict__ out) {
    size_t t = (size_t)blockIdx.x * 256 + threadIdx.x;   // NSEQ*NPOOL
    int k = (int)(t >> 12);
    int i = (int)(t & 4095);
    double bed = (double)be[0];
    bool masked = rank[i] < k;
    out[t] = masked ? (float)bed : (float)(s[i] + c[k] + bed);
}

extern "C" void kernel_launch(void* const* d_in, const int* in_sizes, int n_in,
                              void* d_out, int out_size, void* d_ws, size_t ws_size,
                              hipStream_t stream) {
    const float* x    = (const float*)d_in[0];
    const float* f    = (const float*)d_in[1];
    const float* amat = (const float*)d_in[2];
    const float* dmat = (const float*)d_in[3];
    const float* wf   = (const float*)d_in[4];
    const float* bf   = (const float*)d_in[5];
    const float* w1   = (const float*)d_in[6];
    const float* w2   = (const float*)d_in[7];
    const float* wgr  = (const float*)d_in[8];
    const float* bgr  = (const float*)d_in[9];
    const float* wga  = (const float*)d_in[10];
    const float* bga  = (const float*)d_in[11];
    const float* we   = (const float*)d_in[12];
    const float* be   = (const float*)d_in[13];
    const float* wsq  = (const float*)d_in[14];
    const float* bsq  = (const float*)d_in[15];
    float* out = (float*)d_out;

    char* p = (char*)d_ws;
    const size_t BIG = (size_t)NPOOL * 64 * sizeof(double);   // 2 MB
    double* BUF0 = (double*)p; p += BIG;       // R, then t2
    double* Fin  = (double*)p; p += BIG;
    double* BUF2 = (double*)p; p += BIG;       // t1, then t3
    double* seqe = (double*)p; p += (size_t)NSEQ * SDIM * sizeof(double);
    double* s    = (double*)p; p += (size_t)NPOOL * sizeof(double);
    double* skey = (double*)p; p += (size_t)NSEQ * sizeof(double);
    double* phi_inf  = (double*)p; p += (size_t)NSEQ * GDIM * sizeof(double);
    double* phi_pair = (double*)p; p += (size_t)NSEQ * GDIM * sizeof(double);
    double* hgr   = (double*)p; p += (size_t)NSEQ * GDIM * sizeof(double);
    double* hlast = (double*)p; p += (size_t)NSEQ * 64 * sizeof(double);
    double* c     = (double*)p; p += (size_t)NSEQ * sizeof(double);
    int* order    = (int*)p; p += 2048;
    int* idxs_sel = (int*)p; p += 2048;
    int* rank     = (int*)p; p += (size_t)NPOOL * sizeof(int);
    int* flag     = (int*)p; p += 256;

    double* R  = BUF0;
    double* T1 = BUF2;
    double* T2 = BUF0;   // alias: R dead after first GEMM
    double* T3 = BUF2;   // alias: T1 dead after second GEMM

    k_prep<<<1024, 256, 0, stream>>>(f, wf, bf, Fin, R);
    k_seqe<<<32, 256, 0, stream>>>(x, wsq, bsq, seqe);
    gemm_f64<<<NPOOL / 8, 256, 0, stream>>>(dmat, R, T1);    // t1 = d @ R
    gemm_f64<<<NPOOL / 8, 256, 0, stream>>>(amat, T1, T2);   // t2 = a @ t1
    gemm_f64<<<NPOOL / 8, 256, 0, stream>>>(dmat, T2, T3);   // t3 = d @ t2
    k_head<<<NPOOL / 4, 256, 0, stream>>>(T3, w1, we, s);
    k_sort<<<1, 1024, 0, stream>>>(s, order, skey, idxs_sel);
    k_perk<<<NSEQ, 256, 0, stream>>>(Fin, order, w2, wgr, bgr, wga, bga, phi_inf, phi_pair, hlast);
    k_scan<<<GDIM, 512, 0, stream>>>(phi_inf, phi_pair, hgr);
    k_c<<<NSEQ, 64, 0, stream>>>(hlast, hgr, seqe, we, c);
    k_verify<<<1, 512, 0, stream>>>(skey, c, flag);
    k_fallback<<<1, 256, 0, stream>>>(flag, Fin, order, skey, seqe, w2, wgr, bgr, wga, bga, we, idxs_sel, c);
    k_rank_init<<<NPOOL / 256, 256, 0, stream>>>(rank);
    k_rank_set<<<2, 256, 0, stream>>>(idxs_sel, rank, out);
    k_fill<<<(NSEQ * NPOOL) / 256, 256, 0, stream>>>(s, c, rank, be, out);
}

// Round 2
// 853.779 us; speedup vs baseline: 4.1945x; 4.1945x over previous
//
#include <hip/hip_runtime.h>
#include <math.h>

#define NPOOL 4096
#define NSEQ  512
#define NF    20
#define EDIM  64
#define GDIM  128
#define SDIM  16
#define ALPH  20

__device__ __forceinline__ double relu_d(double x){ return x > 0.0 ? x : 0.0; }
__device__ __forceinline__ double sigm_d(double x){ return 1.0 / (1.0 + exp(-x)); }

// Fin[i][e] = f @ w_feat + b_feat (f64); R = relu(Fin)
__global__ __launch_bounds__(256) void k_prep(const float* __restrict__ f, const float* __restrict__ wf,
                       const float* __restrict__ bf, double* __restrict__ Fin, double* __restrict__ R) {
    int t = blockIdx.x * 256 + threadIdx.x;   // NPOOL*EDIM
    int i = t >> 6, e = t & 63;
    double acc = (double)bf[e];
#pragma unroll
    for (int j = 0; j < NF; ++j)
        acc += (double)f[i * NF + j] * (double)wf[j * EDIM + e];
    Fin[t] = acc;
    R[t] = acc > 0.0 ? acc : 0.0;
}

// seq_embed = x @ w_seq + b_seq (f64)
__global__ __launch_bounds__(256) void k_seqe(const float* __restrict__ x, const float* __restrict__ wsq,
                       const float* __restrict__ bsq, double* __restrict__ seqe) {
    int t = blockIdx.x * 256 + threadIdx.x;   // NSEQ*SDIM = 8192
    int k = t >> 4, s = t & 15;
    double acc = (double)bsq[s];
#pragma unroll
    for (int q = 0; q < ALPH; ++q)
        acc += (double)x[k * ALPH + q] * (double)wsq[q * SDIM + s];
    seqe[t] = acc;
}

// C(4096x64 f64) = A(4096x4096 f32) @ B(4096x64 f64).  BM=8, BK=64.
__global__ __launch_bounds__(256) void gemm_f64(const float* __restrict__ A, const double* __restrict__ B,
                                                double* __restrict__ C) {
    const int N = NPOOL;
    __shared__ double Bs[64 * 64];   // 32 KB
    __shared__ double As[8 * 64];    // 4 KB
    int tid = threadIdx.x;
    int c = tid & 63;
    int rg = tid >> 6;               // 0..3
    int row0 = blockIdx.x * 8;
    double acc0 = 0.0, acc1 = 0.0;
    for (int kt = 0; kt < N; kt += 64) {
        const double* Bt = B + (size_t)kt * 64;
#pragma unroll
        for (int i = 0; i < 16; ++i) {
            int idx = i * 256 + tid;
            Bs[idx] = Bt[idx];
        }
#pragma unroll
        for (int i = 0; i < 2; ++i) {
            int idx = i * 256 + tid;
            int r = idx >> 6, kk = idx & 63;
            As[idx] = (double)A[(size_t)(row0 + r) * N + kt + kk];
        }
        __syncthreads();
        const double* As0 = As + rg * 64;
        const double* As1 = As + (rg + 4) * 64;
#pragma unroll
        for (int kk = 0; kk < 64; ++kk) {
            double b = Bs[kk * 64 + c];
            acc0 = fma(As0[kk], b, acc0);
            acc1 = fma(As1[kk], b, acc1);
        }
        __syncthreads();
    }
    C[(size_t)(row0 + rg) * 64 + c] = acc0;
    C[(size_t)(row0 + rg + 4) * 64 + c] = acc1;
}

// s[i] = relu(T3[i,:] @ w_gcn1) . w_edge[0:64]   (one wave per row)
__global__ __launch_bounds__(256) void k_head(const double* __restrict__ T3, const float* __restrict__ w1,
                       const float* __restrict__ we, double* __restrict__ s) {
    int row = (blockIdx.x * 256 + threadIdx.x) >> 6;
    int e = threadIdx.x & 63;
    const double* r = T3 + (size_t)row * 64;
    double h = 0.0;
#pragma unroll
    for (int c = 0; c < 64; ++c)
        h += r[c] * (double)w1[c * 64 + e];
    double p = (h > 0.0 ? h : 0.0) * (double)we[e];
    for (int off = 32; off; off >>= 1) p += __shfl_down(p, off, 64);
    if (e == 0) s[row] = p;
}

// full bitonic sort of 4096 (desc by key, asc by index on ties)
__global__ __launch_bounds__(1024) void k_sort(const double* __restrict__ s, int* __restrict__ order,
                        double* __restrict__ skey) {
    __shared__ double key[NPOOL];
    __shared__ int    idx[NPOOL];
    for (int t = threadIdx.x; t < NPOOL; t += 1024) { key[t] = s[t]; idx[t] = t; }
    __syncthreads();
    for (int k = 2; k <= NPOOL; k <<= 1) {
        for (int j = k >> 1; j > 0; j >>= 1) {
            for (int t = threadIdx.x; t < NPOOL; t += 1024) {
                int l = t ^ j;
                if (l > t) {
                    double ka = key[t], kb = key[l];
                    int ia = idx[t], ib = idx[l];
                    bool aLess = (ka > kb) || (ka == kb && ia < ib);  // "earlier in final order"
                    bool asc = ((t & k) == 0);
                    bool doSwap = asc ? !aLess : aLess;
                    if (doSwap) { key[t] = kb; key[l] = ka; idx[t] = ib; idx[l] = ia; }
                }
            }
            __syncthreads();
        }
    }
    for (int t = threadIdx.x; t < NSEQ; t += 1024) {
        order[t] = idx[t]; skey[t] = key[t];
    }
}

// orderB[t] = order[0] (repeat-regime hypothesis)
__global__ __launch_bounds__(512) void k_orderB(const int* __restrict__ order, int* __restrict__ orderB) {
    orderB[threadIdx.x] = order[0];
}

// per-k parallel recurrence pieces for a given selection sequence `order`
__global__ __launch_bounds__(256) void k_perk(const double* __restrict__ Fin, const int* __restrict__ order,
                       const float* __restrict__ w2, const float* __restrict__ wgr, const float* __restrict__ bgr,
                       const float* __restrict__ wga, const float* __restrict__ bga,
                       double* __restrict__ phi_inf, double* __restrict__ phi_pair, double* __restrict__ hlast) {
    const double r2 = 0.70710678118654752440;
    const double r3 = 0.57735026918962576451;
    __shared__ double u[4][64];
    __shared__ double comb[3][64];
    __shared__ double v[3][64];
    __shared__ double hgg[3][2][GDIM];
    int k = blockIdx.x;
    int t = threadIdx.x;
    {
        int w = t >> 6, e = t & 63;
        int j = k - 3 + w;
        u[w][e] = (j >= 0) ? Fin[(size_t)order[j] * 64 + e] : 0.0;
    }
    __syncthreads();
    if (t < 192) {
        int w = t >> 6, e = t & 63;
        double dh_km3 = (k - 3 == 0) ? r2 : r3;
        double dh_km2 = (k - 2 == 0) ? r2 : r3;
        double dh_km1 = (k - 1 == 0) ? r2 : r3;
        double outer, c0, c1, c2, c3;
        if (w == 0) {        // v_{k-2} (final form)
            outer = dh_km2; c0 = dh_km3; c1 = dh_km2; c2 = dh_km1; c3 = 0.0;
        } else if (w == 1) { // v_{k-1}^{(k)}
            outer = dh_km1; c0 = 0.0; c1 = dh_km2; c2 = dh_km1; c3 = r2;
        } else {             // v_k^{(k)}
            if (k == 0) { outer = 1.0; c0 = c1 = c2 = 0.0; c3 = 1.0; }
            else        { outer = r2;  c0 = c1 = 0.0; c2 = dh_km1; c3 = r2; }
        }
        comb[w][e] = outer * (c0 * u[0][e] + c1 * u[1][e] + c2 * u[2][e] + c3 * u[3][e]);
    }
    __syncthreads();
    if (t < 192) {
        int w = t >> 6, e = t & 63;
        double acc = 0.0;
#pragma unroll
        for (int j = 0; j < 64; ++j)
            acc += comb[w][j] * (double)w2[j * 64 + e];
        v[w][e] = acc;
    }
    __syncthreads();
    for (int rep = 0; rep < 3; ++rep) {
        int d = t & 127, g = t >> 7;
        const float* W = g ? wga : wgr;
        const float* B = g ? bga : bgr;
        double acc = (double)B[d];
#pragma unroll
        for (int j = 0; j < 64; ++j)
            acc += v[rep][j] * (double)W[j * GDIM + d];
        hgg[rep][g][d] = acc;
    }
    __syncthreads();
    if (t < 128) {
        if (k >= 2) phi_inf[(size_t)(k - 2) * GDIM + t] = hgg[0][0][t] * sigm_d(hgg[0][1][t]);
        double pp = hgg[2][0][t] * sigm_d(hgg[2][1][t]);
        if (k >= 1) pp += hgg[1][0][t] * sigm_d(hgg[1][1][t]);
        phi_pair[(size_t)k * GDIM + t] = pp;
    } else if (t < 192) {
        hlast[(size_t)k * 64 + (t - 128)] = v[2][t - 128];
    }
}

// per-dim prefix scan: hgr[k] = sum_{j<=k-2} phi_inf[j] + phi_pair[k]
__global__ __launch_bounds__(512) void k_scan(const double* __restrict__ phi_inf, const double* __restrict__ phi_pair,
                       double* __restrict__ hgr) {
    __shared__ double sb[NSEQ];
    int d = blockIdx.x, t = threadIdx.x;
    sb[t] = (t >= 2) ? phi_inf[(size_t)(t - 2) * GDIM + d] : 0.0;
    for (int off = 1; off < NSEQ; off <<= 1) {
        __syncthreads();
        double add = (t >= off) ? sb[t - off] : 0.0;
        __syncthreads();
        sb[t] += add;
    }
    __syncthreads();
    hgr[(size_t)t * GDIM + d] = sb[t] + phi_pair[(size_t)t * GDIM + d];
}

// c_k from carried (k-1) state; one wave per k
__global__ __launch_bounds__(64) void k_c(const double* __restrict__ hlast, const double* __restrict__ hgr,
                   const double* __restrict__ seqe, const float* __restrict__ we, double* __restrict__ c) {
    int k = blockIdx.x, j = threadIdx.x;
    double ts = 0.0;
    if (k > 0) {
        ts += relu_d(hlast[(size_t)(k - 1) * 64 + j]) * (double)we[64 + j];
        ts += relu_d(hgr[(size_t)(k - 1) * GDIM + j]) * (double)we[144 + j];
        ts += relu_d(hgr[(size_t)(k - 1) * GDIM + 64 + j]) * (double)we[208 + j];
    }
    if (j < 16) ts += relu_d(seqe[(size_t)k * SDIM + j]) * (double)we[128 + j];
    for (int off = 32; off; off >>= 1) ts += __shfl_down(ts, off, 64);
    if (j == 0) c[k] = ts;
}

// regime A valid iff skey[t] + cA[t] > 0 for all t>=1
__global__ __launch_bounds__(512) void k_verifyA(const double* __restrict__ skey, const double* __restrict__ cA,
                         int* __restrict__ flagA) {
    __shared__ int bad;
    int t = threadIdx.x;
    if (t == 0) bad = 0;
    __syncthreads();
    if (t >= 1 && !(skey[t] + cA[t] > 0.0)) atomicOr(&bad, 1);
    __syncthreads();
    if (t == 0) flagA[0] = bad;
}

// regime B valid iff skey[1] + cB[k] <= 0 for all k>=1
__global__ __launch_bounds__(512) void k_verifyB(const double* __restrict__ skey, const double* __restrict__ cB,
                         int* __restrict__ flagB) {
    __shared__ int bad;
    int t = threadIdx.x;
    if (t == 0) bad = 0;
    __syncthreads();
    if (t >= 1 && (skey[1] + cB[t] > 0.0)) atomicOr(&bad, 1);
    __syncthreads();
    if (t == 0) flagB[0] = bad;
}

// pick regime: mode 0 = advance (A), 1 = repeat (B), 2 = fallback
__global__ __launch_bounds__(512) void k_select(const int* __restrict__ flagA, const int* __restrict__ flagB,
                        const double* __restrict__ cA, const double* __restrict__ cB,
                        const int* __restrict__ order, double* __restrict__ c,
                        int* __restrict__ idxs_sel, int* __restrict__ mode) {
    int t = threadIdx.x;
    if (flagA[0] == 0) {
        c[t] = cA[t]; idxs_sel[t] = order[t];
        if (t == 0) mode[0] = 0;
    } else if (flagB[0] == 0) {
        c[t] = cB[t]; idxs_sel[t] = order[0];
        if (t == 0) mode[0] = 1;
    } else {
        if (t == 0) mode[0] = 2;
    }
}

// exact sequential fallback (runs only when both fast paths invalid)
__global__ __launch_bounds__(256) void k_fallback(const int* __restrict__ mode,
        const double* __restrict__ Fin, const int* __restrict__ order, const double* __restrict__ skey,
        const double* __restrict__ seqe,
        const float* __restrict__ w2, const float* __restrict__ wgr, const float* __restrict__ bgr,
        const float* __restrict__ wga, const float* __restrict__ bga, const float* __restrict__ we,
        int* __restrict__ idxs_sel, double* __restrict__ c) {
    if (mode[0] != 2) return;
    const double r2 = 0.70710678118654752440;
    const double r3 = 0.57735026918962576451;
    __shared__ double u[4][64];
    __shared__ double comb[3][64];
    __shared__ double v[3][64];
    __shared__ double hgg[3][2][GDIM];
    __shared__ double Phi[GDIM], hgraph[GDIM], hlastS[64];
    __shared__ int selS, ptrS, minS_;
    int t = threadIdx.x;
    if (t < 64) { u[0][t] = u[1][t] = u[2][t] = u[3][t] = 0.0; hlastS[t] = 0.0; }
    if (t < 128) { Phi[t] = 0.0; hgraph[t] = 0.0; }
    if (t == 0) { ptrS = 0; minS_ = 0x7fffffff; }
    __syncthreads();
    for (int k = 0; k < NSEQ; ++k) {
        if (t < 64) {
            int j = t;
            double ts = relu_d(hlastS[j]) * (double)we[64 + j]
                      + relu_d(hgraph[j]) * (double)we[144 + j]
                      + relu_d(hgraph[64 + j]) * (double)we[208 + j];
            if (j < 16) ts += relu_d(seqe[(size_t)k * SDIM + j]) * (double)we[128 + j];
            for (int off = 32; off; off >>= 1) ts += __shfl_down(ts, off, 64);
            if (j == 0) {
                c[k] = ts;
                int ptr = ptrS, idx;
                if (ptr == 0) { idx = order[0]; minS_ = idx; ptrS = 1; }
                else if (skey[ptr] + ts > 0.0) {
                    idx = order[ptr];
                    if (idx < minS_) minS_ = idx;
                    ptrS = ptr + 1;
                } else idx = minS_;
                selS = idx;
                idxs_sel[k] = idx;
            }
        }
        __syncthreads();
        int idx = selS;
        if (t < 64) u[k & 3][t] = Fin[(size_t)idx * 64 + t];
        __syncthreads();
        if (t < 192) {
            int w = t >> 6, e = t & 63;
            double dh_km3 = (k - 3 == 0) ? r2 : r3;
            double dh_km2 = (k - 2 == 0) ? r2 : r3;
            double dh_km1 = (k - 1 == 0) ? r2 : r3;
            double outer, c0, c1, c2, c3;
            if (w == 0) {
                outer = dh_km2; c0 = dh_km3; c1 = dh_km2; c2 = dh_km1; c3 = 0.0;
            } else if (w == 1) {
                outer = dh_km1; c0 = 0.0; c1 = dh_km2; c2 = dh_km1; c3 = r2;
            } else {
                if (k == 0) { outer = 1.0; c0 = c1 = c2 = 0.0; c3 = 1.0; }
                else        { outer = r2;  c0 = c1 = 0.0; c2 = dh_km1; c3 = r2; }
            }
            double uu0 = u[(k - 3) & 3][e], uu1 = u[(k - 2) & 3][e], uu2 = u[(k - 1) & 3][e], uu3 = u[k & 3][e];
            comb[w][e] = outer * (c0 * uu0 + c1 * uu1 + c2 * uu2 + c3 * uu3);
        }
        __syncthreads();
        if (t < 192) {
            int w = t >> 6, e = t & 63;
            double acc = 0.0;
#pragma unroll
            for (int j = 0; j < 64; ++j)
                acc += comb[w][j] * (double)w2[j * 64 + e];
            v[w][e] = acc;
        }
        __syncthreads();
        for (int rep = 0; rep < 3; ++rep) {
            int d = t & 127, g = t >> 7;
            const float* W = g ? wga : wgr;
            const float* B = g ? bga : bgr;
            double acc = (double)B[d];
#pragma unroll
            for (int j = 0; j < 64; ++j)
                acc += v[rep][j] * (double)W[j * GDIM + d];
            hgg[rep][g][d] = acc;
        }
        __syncthreads();
        if (t < 128) {
            if (k >= 2) Phi[t] += hgg[0][0][t] * sigm_d(hgg[0][1][t]);
            double hg = Phi[t] + hgg[2][0][t] * sigm_d(hgg[2][1][t]);
            if (k >= 1) hg += hgg[1][0][t] * sigm_d(hgg[1][1][t]);
            hgraph[t] = hg;
        } else if (t < 192) {
            hlastS[t - 128] = v[2][t - 128];
        }
        __syncthreads();
    }
}

__global__ __launch_bounds__(256) void k_rank_init(int* __restrict__ rank) {
    rank[blockIdx.x * 256 + threadIdx.x] = 1 << 30;
}

__global__ __launch_bounds__(256) void k_rank_set(const int* __restrict__ idxs_sel, int* __restrict__ rank,
                           float* __restrict__ out) {
    int t = blockIdx.x * 256 + threadIdx.x;
    if (t < NSEQ) {
        atomicMin(&rank[idxs_sel[t]], t);
        out[(size_t)NSEQ * NPOOL + t] = (float)idxs_sel[t];
    }
}

__global__ __launch_bounds__(256) void k_fill(const double* __restrict__ s, const double* __restrict__ c,
                       const int* __restrict__ rank, const float* __restrict__ be, float* __restrict__ out) {
    size_t t = (size_t)blockIdx.x * 256 + threadIdx.x;   // NSEQ*NPOOL
    int k = (int)(t >> 12);
    int i = (int)(t & 4095);
    double bed = (double)be[0];
    bool masked = rank[i] < k;
    out[t] = masked ? (float)bed : (float)(s[i] + c[k] + bed);
}

extern "C" void kernel_launch(void* const* d_in, const int* in_sizes, int n_in,
                              void* d_out, int out_size, void* d_ws, size_t ws_size,
                              hipStream_t stream) {
    const float* x    = (const float*)d_in[0];
    const float* f    = (const float*)d_in[1];
    const float* amat = (const float*)d_in[2];
    const float* dmat = (const float*)d_in[3];
    const float* wf   = (const float*)d_in[4];
    const float* bf   = (const float*)d_in[5];
    const float* w1   = (const float*)d_in[6];
    const float* w2   = (const float*)d_in[7];
    const float* wgr  = (const float*)d_in[8];
    const float* bgr  = (const float*)d_in[9];
    const float* wga  = (const float*)d_in[10];
    const float* bga  = (const float*)d_in[11];
    const float* we   = (const float*)d_in[12];
    const float* be   = (const float*)d_in[13];
    const float* wsq  = (const float*)d_in[14];
    const float* bsq  = (const float*)d_in[15];
    float* out = (float*)d_out;

    char* p = (char*)d_ws;
    const size_t BIG = (size_t)NPOOL * 64 * sizeof(double);   // 2 MB
    double* BUF0 = (double*)p; p += BIG;       // R, then t2
    double* Fin  = (double*)p; p += BIG;
    double* BUF2 = (double*)p; p += BIG;       // t1, then t3
    double* seqe = (double*)p; p += (size_t)NSEQ * SDIM * sizeof(double);
    double* s    = (double*)p; p += (size_t)NPOOL * sizeof(double);
    double* skey = (double*)p; p += (size_t)NSEQ * sizeof(double);
    double* phi_inf  = (double*)p; p += (size_t)NSEQ * GDIM * sizeof(double);
    double* phi_pair = (double*)p; p += (size_t)NSEQ * GDIM * sizeof(double);
    double* hgr   = (double*)p; p += (size_t)NSEQ * GDIM * sizeof(double);
    double* hlast = (double*)p; p += (size_t)NSEQ * 64 * sizeof(double);
    double* cA    = (double*)p; p += (size_t)NSEQ * sizeof(double);
    double* cB    = (double*)p; p += (size_t)NSEQ * sizeof(double);
    double* c     = (double*)p; p += (size_t)NSEQ * sizeof(double);
    int* order    = (int*)p; p += 2048;
    int* orderB   = (int*)p; p += 2048;
    int* idxs_sel = (int*)p; p += 2048;
    int* rank     = (int*)p; p += (size_t)NPOOL * sizeof(int);
    int* flagA    = (int*)p; p += 256;
    int* flagB    = (int*)p; p += 256;
    int* mode     = (int*)p; p += 256;

    double* R  = BUF0;
    double* T1 = BUF2;
    double* T2 = BUF0;   // alias: R dead after first GEMM
    double* T3 = BUF2;   // alias: T1 dead after second GEMM

    k_prep<<<1024, 256, 0, stream>>>(f, wf, bf, Fin, R);
    k_seqe<<<32, 256, 0, stream>>>(x, wsq, bsq, seqe);
    gemm_f64<<<NPOOL / 8, 256, 0, stream>>>(dmat, R, T1);    // t1 = d @ R
    gemm_f64<<<NPOOL / 8, 256, 0, stream>>>(amat, T1, T2);   // t2 = a @ t1
    gemm_f64<<<NPOOL / 8, 256, 0, stream>>>(dmat, T2, T3);   // t3 = d @ t2
    k_head<<<NPOOL / 4, 256, 0, stream>>>(T3, w1, we, s);
    k_sort<<<1, 1024, 0, stream>>>(s, order, skey);

    // hypothesis A: selection follows sorted order
    k_perk<<<NSEQ, 256, 0, stream>>>(Fin, order, w2, wgr, bgr, wga, bga, phi_inf, phi_pair, hlast);
    k_scan<<<GDIM, 512, 0, stream>>>(phi_inf, phi_pair, hgr);
    k_c<<<NSEQ, 64, 0, stream>>>(hlast, hgr, seqe, we, cA);
    k_verifyA<<<1, 512, 0, stream>>>(skey, cA, flagA);

    // hypothesis B: step 0 picks order[0], every later step re-picks it
    k_orderB<<<1, 512, 0, stream>>>(order, orderB);
    k_perk<<<NSEQ, 256, 0, stream>>>(Fin, orderB, w2, wgr, bgr, wga, bga, phi_inf, phi_pair, hlast);
    k_scan<<<GDIM, 512, 0, stream>>>(phi_inf, phi_pair, hgr);
    k_c<<<NSEQ, 64, 0, stream>>>(hlast, hgr, seqe, we, cB);
    k_verifyB<<<1, 512, 0, stream>>>(skey, cB, flagB);

    k_select<<<1, 512, 0, stream>>>(flagA, flagB, cA, cB, order, c, idxs_sel, mode);
    k_fallback<<<1, 256, 0, stream>>>(mode, Fin, order, skey, seqe, w2, wgr, bgr, wga, bga, we, idxs_sel, c);

    k_rank_init<<<NPOOL / 256, 256, 0, stream>>>(rank);
    k_rank_set<<<2, 256, 0, stream>>>(idxs_sel, rank, out);
    k_fill<<<(NSEQ * NPOOL) / 256, 256, 0, stream>>>(s, c, rank, be, out);
}

// Round 3
// 662.371 us; speedup vs baseline: 5.4066x; 1.2890x over previous
//
#include <hip/hip_runtime.h>
#include <math.h>

#define NPOOL 4096
#define NSEQ  512
#define NF    20
#define EDIM  64
#define GDIM  128
#define SDIM  16
#define ALPH  20
#define SPLITK 8
#define KSLICE (NPOOL / SPLITK)   // 512

__device__ __forceinline__ double relu_d(double x){ return x > 0.0 ? x : 0.0; }
__device__ __forceinline__ double sigm_d(double x){ return 1.0 / (1.0 + exp(-x)); }

// Fin[i][e] = f @ w_feat + b_feat (f64); R = relu(Fin)
__global__ __launch_bounds__(256) void k_prep(const float* __restrict__ f, const float* __restrict__ wf,
                       const float* __restrict__ bf, double* __restrict__ Fin, double* __restrict__ R) {
    int t = blockIdx.x * 256 + threadIdx.x;   // NPOOL*EDIM
    int i = t >> 6, e = t & 63;
    double acc = (double)bf[e];
#pragma unroll
    for (int j = 0; j < NF; ++j)
        acc += (double)f[i * NF + j] * (double)wf[j * EDIM + e];
    Fin[t] = acc;
    R[t] = acc > 0.0 ? acc : 0.0;
}

// seq_embed = x @ w_seq + b_seq (f64)
__global__ __launch_bounds__(256) void k_seqe(const float* __restrict__ x, const float* __restrict__ wsq,
                       const float* __restrict__ bsq, double* __restrict__ seqe) {
    int t = blockIdx.x * 256 + threadIdx.x;   // NSEQ*SDIM = 8192
    int k = t >> 4, s = t & 15;
    double acc = (double)bsq[s];
#pragma unroll
    for (int q = 0; q < ALPH; ++q)
        acc += (double)x[k * ALPH + q] * (double)wsq[q * SDIM + s];
    seqe[t] = acc;
}

__global__ __launch_bounds__(256) void k_zero(double* __restrict__ buf) {
    buf[(size_t)blockIdx.x * 256 + threadIdx.x] = 0.0;
}

// C(4096x64 f64) += A(4096x4096 f32) @ B(4096x64 f64), split-K.
// grid (64 row-blocks, SPLITK k-slices), 256 threads, 4x4 register tile.
__global__ __launch_bounds__(256) void gemm_f64_sk(const float* __restrict__ A, const double* __restrict__ B,
                                                   double* __restrict__ C) {
    __shared__ double As[32][66];   // [k][row], padded
    __shared__ double Bs[32][66];   // [k][col], padded
    int t  = threadIdx.x;
    int tx = t & 15;                // col group
    int ty = t >> 4;                // row group
    int row0 = blockIdx.x * 64;
    int k0   = blockIdx.y * KSLICE;
    double acc[4][4] = {};
    for (int kt = k0; kt < k0 + KSLICE; kt += 32) {
        // stage A: 64 rows x 32 k (f32 -> f64, transposed to [k][row])
        {
            int r = t >> 2, kq = t & 3;
            const float* Ap = A + (size_t)(row0 + r) * NPOOL + kt + kq * 8;
            float4 f0 = *(const float4*)Ap;
            float4 f1 = *(const float4*)(Ap + 4);
            int kb = kq * 8;
            As[kb + 0][r] = (double)f0.x; As[kb + 1][r] = (double)f0.y;
            As[kb + 2][r] = (double)f0.z; As[kb + 3][r] = (double)f0.w;
            As[kb + 4][r] = (double)f1.x; As[kb + 5][r] = (double)f1.y;
            As[kb + 6][r] = (double)f1.z; As[kb + 7][r] = (double)f1.w;
        }
        // stage B: 32 k-rows x 64 cols
        {
            int kr = t >> 3, cq = t & 7;
            const double* Bp = B + (size_t)(kt + kr) * 64 + cq * 8;
            double2 b0 = *(const double2*)(Bp + 0);
            double2 b1 = *(const double2*)(Bp + 2);
            double2 b2 = *(const double2*)(Bp + 4);
            double2 b3 = *(const double2*)(Bp + 6);
            int cb = cq * 8;
            Bs[kr][cb + 0] = b0.x; Bs[kr][cb + 1] = b0.y;
            Bs[kr][cb + 2] = b1.x; Bs[kr][cb + 3] = b1.y;
            Bs[kr][cb + 4] = b2.x; Bs[kr][cb + 5] = b2.y;
            Bs[kr][cb + 6] = b3.x; Bs[kr][cb + 7] = b3.y;
        }
        __syncthreads();
#pragma unroll
        for (int kk = 0; kk < 32; ++kk) {
            const double2* ap = (const double2*)&As[kk][ty * 4];
            const double2* bp = (const double2*)&Bs[kk][tx * 4];
            double2 a01 = ap[0], a23 = ap[1];
            double2 b01 = bp[0], b23 = bp[1];
            double a[4] = {a01.x, a01.y, a23.x, a23.y};
            double b[4] = {b01.x, b01.y, b23.x, b23.y};
#pragma unroll
            for (int i = 0; i < 4; ++i)
#pragma unroll
                for (int j = 0; j < 4; ++j)
                    acc[i][j] = fma(a[i], b[j], acc[i][j]);
        }
        __syncthreads();
    }
    double* Cp = C + (size_t)(row0 + ty * 4) * 64 + tx * 4;
#pragma unroll
    for (int i = 0; i < 4; ++i)
#pragma unroll
        for (int j = 0; j < 4; ++j)
            unsafeAtomicAdd(&Cp[(size_t)i * 64 + j], acc[i][j]);
}

// s[i] = relu(T3[i,:] @ w_gcn1) . w_edge[0:64]   (one wave per row)
__global__ __launch_bounds__(256) void k_head(const double* __restrict__ T3, const float* __restrict__ w1,
                       const float* __restrict__ we, double* __restrict__ s) {
    int row = (blockIdx.x * 256 + threadIdx.x) >> 6;
    int e = threadIdx.x & 63;
    const double* r = T3 + (size_t)row * 64;
    double h = 0.0;
#pragma unroll
    for (int c = 0; c < 64; ++c)
        h += r[c] * (double)w1[c * 64 + e];
    double p = (h > 0.0 ? h : 0.0) * (double)we[e];
    for (int off = 32; off; off >>= 1) p += __shfl_down(p, off, 64);
    if (e == 0) s[row] = p;
}

// full bitonic sort of 4096 (desc by key, asc by index on ties); also emits orderB
__global__ __launch_bounds__(1024) void k_sort(const double* __restrict__ s, int* __restrict__ order,
                        double* __restrict__ skey, int* __restrict__ orderB) {
    __shared__ double key[NPOOL];
    __shared__ int    idx[NPOOL];
    for (int t = threadIdx.x; t < NPOOL; t += 1024) { key[t] = s[t]; idx[t] = t; }
    __syncthreads();
    for (int k = 2; k <= NPOOL; k <<= 1) {
        for (int j = k >> 1; j > 0; j >>= 1) {
            for (int t = threadIdx.x; t < NPOOL; t += 1024) {
                int l = t ^ j;
                if (l > t) {
                    double ka = key[t], kb = key[l];
                    int ia = idx[t], ib = idx[l];
                    bool aLess = (ka > kb) || (ka == kb && ia < ib);
                    bool asc = ((t & k) == 0);
                    bool doSwap = asc ? !aLess : aLess;
                    if (doSwap) { key[t] = kb; key[l] = ka; idx[t] = ib; idx[l] = ia; }
                }
            }
            __syncthreads();
        }
    }
    for (int t = threadIdx.x; t < NSEQ; t += 1024) {
        order[t] = idx[t]; skey[t] = key[t]; orderB[t] = idx[0];
    }
}

// per-k parallel recurrence pieces for a given selection sequence `order`
__global__ __launch_bounds__(256) void k_perk(const double* __restrict__ Fin, const int* __restrict__ order,
                       const float* __restrict__ w2, const float* __restrict__ wgr, const float* __restrict__ bgr,
                       const float* __restrict__ wga, const float* __restrict__ bga,
                       double* __restrict__ phi_inf, double* __restrict__ phi_pair, double* __restrict__ hlast) {
    const double r2 = 0.70710678118654752440;
    const double r3 = 0.57735026918962576451;
    __shared__ double u[4][64];
    __shared__ double comb[3][64];
    __shared__ double v[3][64];
    __shared__ double hgg[3][2][GDIM];
    int k = blockIdx.x;
    int t = threadIdx.x;
    {
        int w = t >> 6, e = t & 63;
        int j = k - 3 + w;
        u[w][e] = (j >= 0) ? Fin[(size_t)order[j] * 64 + e] : 0.0;
    }
    __syncthreads();
    if (t < 192) {
        int w = t >> 6, e = t & 63;
        double dh_km3 = (k - 3 == 0) ? r2 : r3;
        double dh_km2 = (k - 2 == 0) ? r2 : r3;
        double dh_km1 = (k - 1 == 0) ? r2 : r3;
        double outer, c0, c1, c2, c3;
        if (w == 0) {        // v_{k-2} (final form)
            outer = dh_km2; c0 = dh_km3; c1 = dh_km2; c2 = dh_km1; c3 = 0.0;
        } else if (w == 1) { // v_{k-1}^{(k)}
            outer = dh_km1; c0 = 0.0; c1 = dh_km2; c2 = dh_km1; c3 = r2;
        } else {             // v_k^{(k)}
            if (k == 0) { outer = 1.0; c0 = c1 = c2 = 0.0; c3 = 1.0; }
            else        { outer = r2;  c0 = c1 = 0.0; c2 = dh_km1; c3 = r2; }
        }
        comb[w][e] = outer * (c0 * u[0][e] + c1 * u[1][e] + c2 * u[2][e] + c3 * u[3][e]);
    }
    __syncthreads();
    if (t < 192) {
        int w = t >> 6, e = t & 63;
        double acc = 0.0;
#pragma unroll
        for (int j = 0; j < 64; ++j)
            acc += comb[w][j] * (double)w2[j * 64 + e];
        v[w][e] = acc;
    }
    __syncthreads();
    for (int rep = 0; rep < 3; ++rep) {
        int d = t & 127, g = t >> 7;
        const float* W = g ? wga : wgr;
        const float* B = g ? bga : bgr;
        double acc = (double)B[d];
#pragma unroll
        for (int j = 0; j < 64; ++j)
            acc += v[rep][j] * (double)W[j * GDIM + d];
        hgg[rep][g][d] = acc;
    }
    __syncthreads();
    if (t < 128) {
        if (k >= 2) phi_inf[(size_t)(k - 2) * GDIM + t] = hgg[0][0][t] * sigm_d(hgg[0][1][t]);
        double pp = hgg[2][0][t] * sigm_d(hgg[2][1][t]);
        if (k >= 1) pp += hgg[1][0][t] * sigm_d(hgg[1][1][t]);
        phi_pair[(size_t)k * GDIM + t] = pp;
    } else if (t < 192) {
        hlast[(size_t)k * 64 + (t - 128)] = v[2][t - 128];
    }
}

// per-dim prefix scan: hgr[k] = sum_{j<=k-2} phi_inf[j] + phi_pair[k]
__global__ __launch_bounds__(512) void k_scan(const double* __restrict__ phi_inf, const double* __restrict__ phi_pair,
                       double* __restrict__ hgr) {
    __shared__ double sb[NSEQ];
    int d = blockIdx.x, t = threadIdx.x;
    sb[t] = (t >= 2) ? phi_inf[(size_t)(t - 2) * GDIM + d] : 0.0;
    for (int off = 1; off < NSEQ; off <<= 1) {
        __syncthreads();
        double add = (t >= off) ? sb[t - off] : 0.0;
        __syncthreads();
        sb[t] += add;
    }
    __syncthreads();
    hgr[(size_t)t * GDIM + d] = sb[t] + phi_pair[(size_t)t * GDIM + d];
}

// c_k from carried (k-1) state; one wave per k
__global__ __launch_bounds__(64) void k_c(const double* __restrict__ hlast, const double* __restrict__ hgr,
                   const double* __restrict__ seqe, const float* __restrict__ we, double* __restrict__ c) {
    int k = blockIdx.x, j = threadIdx.x;
    double ts = 0.0;
    if (k > 0) {
        ts += relu_d(hlast[(size_t)(k - 1) * 64 + j]) * (double)we[64 + j];
        ts += relu_d(hgr[(size_t)(k - 1) * GDIM + j]) * (double)we[144 + j];
        ts += relu_d(hgr[(size_t)(k - 1) * GDIM + 64 + j]) * (double)we[208 + j];
    }
    if (j < 16) ts += relu_d(seqe[(size_t)k * SDIM + j]) * (double)we[128 + j];
    for (int off = 32; off; off >>= 1) ts += __shfl_down(ts, off, 64);
    if (j == 0) c[k] = ts;
}

// regime A valid iff skey[t] + cA[t] > 0 for all t>=1
__global__ __launch_bounds__(512) void k_verifyA(const double* __restrict__ skey, const double* __restrict__ cA,
                         int* __restrict__ flagA) {
    __shared__ int bad;
    int t = threadIdx.x;
    if (t == 0) bad = 0;
    __syncthreads();
    if (t >= 1 && !(skey[t] + cA[t] > 0.0)) atomicOr(&bad, 1);
    __syncthreads();
    if (t == 0) flagA[0] = bad;
}

// regime B valid iff skey[1] + cB[k] <= 0 for all k>=1
__global__ __launch_bounds__(512) void k_verifyB(const double* __restrict__ skey, const double* __restrict__ cB,
                         int* __restrict__ flagB) {
    __shared__ int bad;
    int t = threadIdx.x;
    if (t == 0) bad = 0;
    __syncthreads();
    if (t >= 1 && (skey[1] + cB[t] > 0.0)) atomicOr(&bad, 1);
    __syncthreads();
    if (t == 0) flagB[0] = bad;
}

// pick regime: mode 0 = advance (A), 1 = repeat (B), 2 = fallback
__global__ __launch_bounds__(512) void k_select(const int* __restrict__ flagA, const int* __restrict__ flagB,
                        const double* __restrict__ cA, const double* __restrict__ cB,
                        const int* __restrict__ order, double* __restrict__ c,
                        int* __restrict__ idxs_sel, int* __restrict__ mode) {
    int t = threadIdx.x;
    if (flagA[0] == 0) {
        c[t] = cA[t]; idxs_sel[t] = order[t];
        if (t == 0) mode[0] = 0;
    } else if (flagB[0] == 0) {
        c[t] = cB[t]; idxs_sel[t] = order[0];
        if (t == 0) mode[0] = 1;
    } else {
        if (t == 0) mode[0] = 2;
    }
}

// exact sequential fallback (runs only when both fast paths invalid)
__global__ __launch_bounds__(256) void k_fallback(const int* __restrict__ mode,
        const double* __restrict__ Fin, const int* __restrict__ order, const double* __restrict__ skey,
        const double* __restrict__ seqe,
        const float* __restrict__ w2, const float* __restrict__ wgr, const float* __restrict__ bgr,
        const float* __restrict__ wga, const float* __restrict__ bga, const float* __restrict__ we,
        int* __restrict__ idxs_sel, double* __restrict__ c) {
    if (mode[0] != 2) return;
    const double r2 = 0.70710678118654752440;
    const double r3 = 0.57735026918962576451;
    __shared__ double u[4][64];
    __shared__ double comb[3][64];
    __shared__ double v[3][64];
    __shared__ double hgg[3][2][GDIM];
    __shared__ double Phi[GDIM], hgraph[GDIM], hlastS[64];
    __shared__ int selS, ptrS, minS_;
    int t = threadIdx.x;
    if (t < 64) { u[0][t] = u[1][t] = u[2][t] = u[3][t] = 0.0; hlastS[t] = 0.0; }
    if (t < 128) { Phi[t] = 0.0; hgraph[t] = 0.0; }
    if (t == 0) { ptrS = 0; minS_ = 0x7fffffff; }
    __syncthreads();
    for (int k = 0; k < NSEQ; ++k) {
        if (t < 64) {
            int j = t;
            double ts = relu_d(hlastS[j]) * (double)we[64 + j]
                      + relu_d(hgraph[j]) * (double)we[144 + j]
                      + relu_d(hgraph[64 + j]) * (double)we[208 + j];
            if (j < 16) ts += relu_d(seqe[(size_t)k * SDIM + j]) * (double)we[128 + j];
            for (int off = 32; off; off >>= 1) ts += __shfl_down(ts, off, 64);
            if (j == 0) {
                c[k] = ts;
                int ptr = ptrS, idx;
                if (ptr == 0) { idx = order[0]; minS_ = idx; ptrS = 1; }
                else if (skey[ptr] + ts > 0.0) {
                    idx = order[ptr];
                    if (idx < minS_) minS_ = idx;
                    ptrS = ptr + 1;
                } else idx = minS_;
                selS = idx;
                idxs_sel[k] = idx;
            }
        }
        __syncthreads();
        int idx = selS;
        if (t < 64) u[k & 3][t] = Fin[(size_t)idx * 64 + t];
        __syncthreads();
        if (t < 192) {
            int w = t >> 6, e = t & 63;
            double dh_km3 = (k - 3 == 0) ? r2 : r3;
            double dh_km2 = (k - 2 == 0) ? r2 : r3;
            double dh_km1 = (k - 1 == 0) ? r2 : r3;
            double outer, c0, c1, c2, c3;
            if (w == 0) {
                outer = dh_km2; c0 = dh_km3; c1 = dh_km2; c2 = dh_km1; c3 = 0.0;
            } else if (w == 1) {
                outer = dh_km1; c0 = 0.0; c1 = dh_km2; c2 = dh_km1; c3 = r2;
            } else {
                if (k == 0) { outer = 1.0; c0 = c1 = c2 = 0.0; c3 = 1.0; }
                else        { outer = r2;  c0 = c1 = 0.0; c2 = dh_km1; c3 = r2; }
            }
            double uu0 = u[(k - 3) & 3][e], uu1 = u[(k - 2) & 3][e], uu2 = u[(k - 1) & 3][e], uu3 = u[k & 3][e];
            comb[w][e] = outer * (c0 * uu0 + c1 * uu1 + c2 * uu2 + c3 * uu3);
        }
        __syncthreads();
        if (t < 192) {
            int w = t >> 6, e = t & 63;
            double acc = 0.0;
#pragma unroll
            for (int j = 0; j < 64; ++j)
                acc += comb[w][j] * (double)w2[j * 64 + e];
            v[w][e] = acc;
        }
        __syncthreads();
        for (int rep = 0; rep < 3; ++rep) {
            int d = t & 127, g = t >> 7;
            const float* W = g ? wga : wgr;
            const float* B = g ? bga : bgr;
            double acc = (double)B[d];
#pragma unroll
            for (int j = 0; j < 64; ++j)
                acc += v[rep][j] * (double)W[j * GDIM + d];
            hgg[rep][g][d] = acc;
        }
        __syncthreads();
        if (t < 128) {
            if (k >= 2) Phi[t] += hgg[0][0][t] * sigm_d(hgg[0][1][t]);
            double hg = Phi[t] + hgg[2][0][t] * sigm_d(hgg[2][1][t]);
            if (k >= 1) hg += hgg[1][0][t] * sigm_d(hgg[1][1][t]);
            hgraph[t] = hg;
        } else if (t < 192) {
            hlastS[t - 128] = v[2][t - 128];
        }
        __syncthreads();
    }
}

__global__ __launch_bounds__(256) void k_rank_init(int* __restrict__ rank) {
    rank[blockIdx.x * 256 + threadIdx.x] = 1 << 30;
}

__global__ __launch_bounds__(256) void k_rank_set(const int* __restrict__ idxs_sel, int* __restrict__ rank,
                           float* __restrict__ out) {
    int t = blockIdx.x * 256 + threadIdx.x;
    if (t < NSEQ) {
        atomicMin(&rank[idxs_sel[t]], t);
        out[(size_t)NSEQ * NPOOL + t] = (float)idxs_sel[t];
    }
}

__global__ __launch_bounds__(256) void k_fill(const double* __restrict__ s, const double* __restrict__ c,
                       const int* __restrict__ rank, const float* __restrict__ be, float* __restrict__ out) {
    size_t t = (size_t)blockIdx.x * 256 + threadIdx.x;   // NSEQ*NPOOL
    int k = (int)(t >> 12);
    int i = (int)(t & 4095);
    double bed = (double)be[0];
    bool masked = rank[i] < k;
    out[t] = masked ? (float)bed : (float)(s[i] + c[k] + bed);
}

extern "C" void kernel_launch(void* const* d_in, const int* in_sizes, int n_in,
                              void* d_out, int out_size, void* d_ws, size_t ws_size,
                              hipStream_t stream) {
    const float* x    = (const float*)d_in[0];
    const float* f    = (const float*)d_in[1];
    const float* amat = (const float*)d_in[2];
    const float* dmat = (const float*)d_in[3];
    const float* wf   = (const float*)d_in[4];
    const float* bf   = (const float*)d_in[5];
    const float* w1   = (const float*)d_in[6];
    const float* w2   = (const float*)d_in[7];
    const float* wgr  = (const float*)d_in[8];
    const float* bgr  = (const float*)d_in[9];
    const float* wga  = (const float*)d_in[10];
    const float* bga  = (const float*)d_in[11];
    const float* we   = (const float*)d_in[12];
    const float* be   = (const float*)d_in[13];
    const float* wsq  = (const float*)d_in[14];
    const float* bsq  = (const float*)d_in[15];
    float* out = (float*)d_out;

    char* p = (char*)d_ws;
    const size_t BIG = (size_t)NPOOL * 64 * sizeof(double);   // 2 MB
    double* BUF0 = (double*)p; p += BIG;       // R, then t2
    double* Fin  = (double*)p; p += BIG;
    double* BUF2 = (double*)p; p += BIG;       // t1, then t3
    double* seqe = (double*)p; p += (size_t)NSEQ * SDIM * sizeof(double);
    double* s    = (double*)p; p += (size_t)NPOOL * sizeof(double);
    double* skey = (double*)p; p += (size_t)NSEQ * sizeof(double);
    double* phi_inf  = (double*)p; p += (size_t)NSEQ * GDIM * sizeof(double);
    double* phi_pair = (double*)p; p += (size_t)NSEQ * GDIM * sizeof(double);
    double* hgr   = (double*)p; p += (size_t)NSEQ * GDIM * sizeof(double);
    double* hlast = (double*)p; p += (size_t)NSEQ * 64 * sizeof(double);
    double* cA    = (double*)p; p += (size_t)NSEQ * sizeof(double);
    double* cB    = (double*)p; p += (size_t)NSEQ * sizeof(double);
    double* c     = (double*)p; p += (size_t)NSEQ * sizeof(double);
    int* order    = (int*)p; p += 2048;
    int* orderB   = (int*)p; p += 2048;
    int* idxs_sel = (int*)p; p += 2048;
    int* rank     = (int*)p; p += (size_t)NPOOL * sizeof(int);
    int* flagA    = (int*)p; p += 256;
    int* flagB    = (int*)p; p += 256;
    int* mode     = (int*)p; p += 256;

    double* R  = BUF0;
    double* T1 = BUF2;
    double* T2 = BUF0;   // alias: R dead after first GEMM
    double* T3 = BUF2;   // alias: T1 dead after second GEMM

    dim3 ggrid(NPOOL / 64, SPLITK);

    k_prep<<<1024, 256, 0, stream>>>(f, wf, bf, Fin, R);
    k_seqe<<<32, 256, 0, stream>>>(x, wsq, bsq, seqe);

    k_zero<<<1024, 256, 0, stream>>>(T1);
    gemm_f64_sk<<<ggrid, 256, 0, stream>>>(dmat, R, T1);    // t1 = d @ R
    k_zero<<<1024, 256, 0, stream>>>(T2);
    gemm_f64_sk<<<ggrid, 256, 0, stream>>>(amat, T1, T2);   // t2 = a @ t1
    k_zero<<<1024, 256, 0, stream>>>(T3);
    gemm_f64_sk<<<ggrid, 256, 0, stream>>>(dmat, T2, T3);   // t3 = d @ t2

    k_head<<<NPOOL / 4, 256, 0, stream>>>(T3, w1, we, s);
    k_sort<<<1, 1024, 0, stream>>>(s, order, skey, orderB);

    // hypothesis A: selection follows sorted order
    k_perk<<<NSEQ, 256, 0, stream>>>(Fin, order, w2, wgr, bgr, wga, bga, phi_inf, phi_pair, hlast);
    k_scan<<<GDIM, 512, 0, stream>>>(phi_inf, phi_pair, hgr);
    k_c<<<NSEQ, 64, 0, stream>>>(hlast, hgr, seqe, we, cA);
    k_verifyA<<<1, 512, 0, stream>>>(skey, cA, flagA);

    // hypothesis B: step 0 picks order[0], every later step re-picks it
    k_perk<<<NSEQ, 256, 0, stream>>>(Fin, orderB, w2, wgr, bgr, wga, bga, phi_inf, phi_pair, hlast);
    k_scan<<<GDIM, 512, 0, stream>>>(phi_inf, phi_pair, hgr);
    k_c<<<NSEQ, 64, 0, stream>>>(hlast, hgr, seqe, we, cB);
    k_verifyB<<<1, 512, 0, stream>>>(skey, cB, flagB);

    k_select<<<1, 512, 0, stream>>>(flagA, flagB, cA, cB, order, c, idxs_sel, mode);
    k_fallback<<<1, 256, 0, stream>>>(mode, Fin, order, skey, seqe, w2, wgr, bgr, wga, bga, we, idxs_sel, c);

    k_rank_init<<<NPOOL / 256, 256, 0, stream>>>(rank);
    k_rank_set<<<2, 256, 0, stream>>>(idxs_sel, rank, out);
    k_fill<<<(NSEQ * NPOOL) / 256, 256, 0, stream>>>(s, c, rank, be, out);
}